// Round 4
// baseline (232.643 us; speedup 1.0000x reference)
//
#include <hip/hip_runtime.h>
#include <cstdint>

// BinarizedLeNet5 / CIFAR10, B=2048.  Round 4: i8-MFMA for all binary layers.
//  k0_pack : weight preprocessing: signed conv1 w + bn params (verbatim) +
//            i8 MFMA B-fragment streams for conv2 / fc1 / fc2.
//  k13     : conv1 fp32 (verbatim round-2 math) -> sign bytes in LDS halo ->
//            conv2 as 10 i8-MFMAs per wave-channel-tile (K=320, zero-padded
//            tap) -> pool (in-register, from D-layout) -> bn2 -> +-1 bytes.
//  k4      : fc1 as i8 GEMM  [2048,4096]x[4096,512] -> bn3 -> +-1 bytes.
//  k5      : fc2 as i8 GEMM  [2048,512]x[512,256] -> bn4 -> clip -> fp32.
//  k6      : fc3 + log_softmax (verbatim round-1, passing).
// All binary-layer sums are exact i32 integers identical to the popc path;
// every float epilogue op-order is verbatim from the absmax-0.0 kernels.
// MFMA layouts (from verified 16x16 maps, K-scaled to i8 K=64):
//   A[m=lane&15][k=(lane>>4)*16+j], B[k=(lane>>4)*16+j][n=lane&15],
//   D[row=m=(lane>>4)*4+r][col=n=lane&15], bytes little-endian in dwords.

#define BSZ 2048

typedef int vi4 __attribute__((ext_vector_type(4)));

__device__ __forceinline__ float sgnf(float w) {
    return (w > 0.f) ? 1.f : ((w < 0.f) ? -1.f : 0.f);
}
__device__ __forceinline__ uint32_t sgnb4(float a, float b, float c, float d) {
    return (a > 0.f ? 1u : 0xFFu) | ((b > 0.f ? 1u : 0xFFu) << 8) |
           ((c > 0.f ? 1u : 0xFFu) << 16) | ((d > 0.f ? 1u : 0xFFu) << 24);
}

// ---------------- k0: all packing ----------------
// grid: [0,512) fc1 frags | [512,544) fc2 frags | 544 conv2 frags
//       | 545 sw1+bnp1 | 546 bnp2 | 547 bnp3+bnp4
__global__ __launch_bounds__(256) void k0_pack(
    const float* __restrict__ c1w, const float* __restrict__ c2w,
    const float* __restrict__ f1w, const float* __restrict__ f2w,
    const float* __restrict__ c1b, const float* __restrict__ c2b,
    const float* __restrict__ f1b, const float* __restrict__ f2b,
    const float* __restrict__ b1g, const float* __restrict__ b1b,
    const float* __restrict__ b1m, const float* __restrict__ b1v,
    const float* __restrict__ b2g, const float* __restrict__ b2b,
    const float* __restrict__ b2m, const float* __restrict__ b2v,
    const float* __restrict__ b3g, const float* __restrict__ b3b,
    const float* __restrict__ b3m, const float* __restrict__ b3v,
    const float* __restrict__ b4g, const float* __restrict__ b4b,
    const float* __restrict__ b4m, const float* __restrict__ b4v,
    float* __restrict__ sw1, uint32_t* __restrict__ wfC2,
    uint32_t* __restrict__ wfF1, uint32_t* __restrict__ wfF2,
    float* __restrict__ bnp1, float* __restrict__ bnp2,
    float* __restrict__ bnp3, float* __restrict__ bnp4) {
    int bid = blockIdx.x, t = threadIdx.x;
    if (bid < 512) {
        // fc1 B-frags: entry e = (nt*64 + s)*64 + l ; o=nt*16+(l&15),
        // k = s*64 + (l>>4)*16 + j  -> byte j = sign(f1w[o*4096 + k])
        int e = bid * 256 + t;
        int l = e & 63, s = (e >> 6) & 63, nt = e >> 12;
        int o = nt * 16 + (l & 15);
        int f0 = s * 64 + (l >> 4) * 16;
        const float4* p4 = (const float4*)(f1w + (size_t)o * 4096 + f0);
        float4 w0 = p4[0], w1 = p4[1], w2 = p4[2], w3 = p4[3];
        uint4 r;
        r.x = sgnb4(w0.x, w0.y, w0.z, w0.w);
        r.y = sgnb4(w1.x, w1.y, w1.z, w1.w);
        r.z = sgnb4(w2.x, w2.y, w2.z, w2.w);
        r.w = sgnb4(w3.x, w3.y, w3.z, w3.w);
        ((uint4*)wfF1)[e] = r;
    } else if (bid < 544) {
        // fc2 B-frags: e = (nt*8 + s)*64 + l
        int e = (bid - 512) * 256 + t;
        int l = e & 63, s = (e >> 6) & 7, nt = e >> 9;
        int o = nt * 16 + (l & 15);
        int f0 = s * 64 + (l >> 4) * 16;
        const float4* p4 = (const float4*)(f2w + (size_t)o * 512 + f0);
        float4 w0 = p4[0], w1 = p4[1], w2 = p4[2], w3 = p4[3];
        uint4 r;
        r.x = sgnb4(w0.x, w0.y, w0.z, w0.w);
        r.y = sgnb4(w1.x, w1.y, w1.z, w1.w);
        r.z = sgnb4(w2.x, w2.y, w2.z, w2.w);
        r.w = sgnb4(w3.x, w3.y, w3.z, w3.w);
        ((uint4*)wfF2)[e] = r;
    } else if (bid == 544) {
        // conv2 B-frags: e = (w*5 + s)*64 + l, tap = 2s + (kq>>1),
        // c = (kq&1)*16 + j ; byte = tap<9 ? sign(c2w[(o*32+c)*9+tap]) : 0
        for (int e = t; e < 1280; e += 256) {
            int l = e & 63, q = e >> 6;
            int s = q % 5, w = q / 5;
            int kq = l >> 4;
            int o = w * 16 + (l & 15);
            int tap = 2 * s + (kq >> 1);
            uint4 r = {0, 0, 0, 0};
            if (tap < 9) {
                int cb = (kq & 1) * 16;
                uint32_t d[4];
#pragma unroll
                for (int dw = 0; dw < 4; dw++) {
                    uint32_t word = 0;
#pragma unroll
                    for (int j = 0; j < 4; j++) {
                        int c = cb + dw * 4 + j;
                        float wv = c2w[(size_t)(o * 32 + c) * 9 + tap];
                        word |= (wv > 0.f ? 1u : 0xFFu) << (j * 8);
                    }
                    d[dw] = word;
                }
                r.x = d[0]; r.y = d[1]; r.z = d[2]; r.w = d[3];
            }
            ((uint4*)wfC2)[e] = r;
        }
    } else if (bid == 545) {
        for (int i = t; i < 1024; i += 256) {
            int o = i >> 5, r = i & 31;
            sw1[i] = (r < 27) ? sgnf(c1w[o * 27 + r]) : 0.f;
        }
        if (t < 32) {
            float inv = __fdiv_rn(b1g[t], __fsqrt_rn(b1v[t] + 1e-5f));
            float add = __fsub_rn(b1b[t], __fmul_rn(b1m[t], inv));
            bnp1[t * 4] = inv; bnp1[t * 4 + 1] = add;
            bnp1[t * 4 + 2] = c1b[t]; bnp1[t * 4 + 3] = 0.f;
        }
    } else if (bid == 546) {
        if (t < 64) {
            float inv = __fdiv_rn(b2g[t], __fsqrt_rn(b2v[t] + 1e-5f));
            float add = __fsub_rn(b2b[t], __fmul_rn(b2m[t], inv));
            bnp2[t * 4] = inv; bnp2[t * 4 + 1] = add;
            bnp2[t * 4 + 2] = c2b[t]; bnp2[t * 4 + 3] = 0.f;
        }
    } else {
        for (int i = t; i < 512; i += 256) {
            float inv = __fdiv_rn(b3g[i], __fsqrt_rn(b3v[i] + 1e-5f));
            float add = __fsub_rn(b3b[i], __fmul_rn(b3m[i], inv));
            bnp3[i * 4] = inv; bnp3[i * 4 + 1] = add;
            bnp3[i * 4 + 2] = f1b[i]; bnp3[i * 4 + 3] = 0.f;
        }
        if (t < 256) {
            float inv = __fdiv_rn(b4g[t], __fsqrt_rn(b4v[t] + 1e-5f));
            float add = __fsub_rn(b4b[t], __fmul_rn(b4m[t], inv));
            bnp4[t * 4] = inv; bnp4[t * 4 + 1] = add;
            bnp4[t * 4 + 2] = f2b[t]; bnp4[t * 4 + 3] = 0.f;
        }
    }
}

// ---------------- k13: conv1 (fp32) + conv2 (i8 MFMA), one block/sample ----
__global__ __launch_bounds__(256) void k13_conv12(
    const float* __restrict__ x, const float* __restrict__ sw,
    const float* __restrict__ bnp1, const uint32_t* __restrict__ wfC2,
    const float* __restrict__ bnp2, uint8_t* __restrict__ fc1A) {
    // halo[yy][xx][c]: yy,xx in 0..17 <-> input coords -1..16, 32 ch bytes
    __shared__ __align__(16) uint8_t halo[18 * 18 * 32];
    int b = blockIdx.x, t = threadIdx.x;
    uint32_t* h32 = (uint32_t*)halo;
    for (int i = t; i < 2592; i += 256) h32[i] = 0;

    // ---- conv1 + pool + bn1 (verbatim round-2 math) -> 32 sign bytes ----
    int py = t >> 4, px = t & 15;
    {
        int y0 = 2 * py - 1, x0 = 2 * px - 1;
        float in[48];
#pragma unroll
        for (int c = 0; c < 3; c++) {
            const float* xc = x + ((size_t)b * 3 + c) * 1024;
#pragma unroll
            for (int i = 0; i < 4; i++) {
                int yy = y0 + i;
                bool ry = (unsigned)yy < 32u;
#pragma unroll
                for (int j = 0; j < 4; j++) {
                    int xx = x0 + j;
                    in[c * 16 + i * 4 + j] =
                        (ry && (unsigned)xx < 32u) ? xc[yy * 32 + xx] : 0.f;
                }
            }
        }
        uint32_t ob[8];
#pragma unroll
        for (int i = 0; i < 8; i++) ob[i] = 0;
#pragma unroll 2
        for (int o = 0; o < 32; o++) {
            const float* wo = sw + o * 32;           // uniform -> s_load
            float a00 = 0.f, a01 = 0.f, a10 = 0.f, a11 = 0.f;
#pragma unroll
            for (int c = 0; c < 3; c++)
#pragma unroll
                for (int ky = 0; ky < 3; ky++)
#pragma unroll
                    for (int kx = 0; kx < 3; kx++) {
                        float wv = wo[c * 9 + ky * 3 + kx];
                        a00 = fmaf(in[c * 16 + ky * 4 + kx], wv, a00);
                        a01 = fmaf(in[c * 16 + ky * 4 + kx + 1], wv, a01);
                        a10 = fmaf(in[c * 16 + (ky + 1) * 4 + kx], wv, a10);
                        a11 = fmaf(in[c * 16 + (ky + 1) * 4 + kx + 1], wv, a11);
                    }
            float4 p = ((const float4*)bnp1)[o];     // uniform -> s_load
            float mx = fmaxf(fmaxf(a00, a01), fmaxf(a10, a11));
            float h = __fadd_rn(mx, p.z);
            float val = __fadd_rn(__fmul_rn(h, p.x), p.y);
            ob[o >> 2] |= (val > 0.f ? 1u : 0xFFu) << ((o & 3) * 8);
        }
        __syncthreads();                             // zero-fill complete
        uint4* dst = (uint4*)(halo + ((py + 1) * 18 + (px + 1)) * 32);
        uint4 v0 = {ob[0], ob[1], ob[2], ob[3]};
        uint4 v1 = {ob[4], ob[5], ob[6], ob[7]};
        dst[0] = v0; dst[1] = v1;
    }

    // ---- conv2 via i8 MFMA ----
    int l = t & 63, w = t >> 6;                      // wave w = out-ch tile
    int kq = l >> 4, ml = l & 15;
    // B-fragments for this wave's 16 out-channels, all 5 K-steps
    vi4 bf[5];
    const vi4* wf = (const vi4*)wfC2;
#pragma unroll
    for (int s = 0; s < 5; s++) bf[s] = wf[(w * 5 + s) * 64 + l];
    // per-lane A addresses: tap = 2s + (kq>>1), c-base = (kq&1)*16
    int offs[5]; bool oks[5];
#pragma unroll
    for (int s = 0; s < 5; s++) {
        int tap = 2 * s + (kq >> 1);
        oks[s] = tap < 9;
        int ky = oks[s] ? tap / 3 : 0, kx = oks[s] ? tap % 3 : 0;
        offs[s] = (ky * 18 + ml + kx) * 32 + (kq & 1) * 16;
    }
    int o = w * 16 + ml;
    float4 p2 = ((const float4*)bnp2)[o];
    __syncthreads();                                 // halo ready
    const vi4 vz = {0, 0, 0, 0};
#pragma unroll 2
    for (int tt = 0; tt < 8; tt++) {
        vi4 acc0 = {0, 0, 0, 0}, acc1 = {0, 0, 0, 0};
        int base0 = (2 * tt) * 576, base1 = (2 * tt + 1) * 576;
#pragma unroll
        for (int s = 0; s < 5; s++) {
            vi4 a0 = oks[s] ? *(const vi4*)(halo + base0 + offs[s]) : vz;
            vi4 a1 = oks[s] ? *(const vi4*)(halo + base1 + offs[s]) : vz;
            acc0 = __builtin_amdgcn_mfma_i32_16x16x64_i8(a0, bf[s], acc0, 0, 0, 0);
            acc1 = __builtin_amdgcn_mfma_i32_16x16x64_i8(a1, bf[s], acc1, 0, 0, 0);
        }
        // D: lane holds rows x=4*kq+r, col=o. pool pairs (r0,r1),(r2,r3) x
        // rows (2tt, 2tt+1) -> pooled (py=tt, px=2kq / 2kq+1)
        int m0 = max(max(acc0[0], acc0[1]), max(acc1[0], acc1[1]));
        int m1 = max(max(acc0[2], acc0[3]), max(acc1[2], acc1[3]));
        float h0 = __fadd_rn((float)m0, p2.z);
        float v0 = __fadd_rn(__fmul_rn(h0, p2.x), p2.y);
        float h1 = __fadd_rn((float)m1, p2.z);
        float v1 = __fadd_rn(__fmul_rn(h1, p2.x), p2.y);
        uint16_t pr = (uint16_t)((v0 > 0.f ? 1u : 0xFFu) |
                                 ((v1 > 0.f ? 1u : 0xFFu) << 8));
        // NCHW flatten: f = o*64 + py*8 + px
        *(uint16_t*)(fc1A + (size_t)b * 4096 + o * 64 + tt * 8 + 2 * kq) = pr;
    }
}

// ---------------- k4: fc1 i8 GEMM [2048,4096]x[4096,512] + bn3 ----------------
// block = 64M x 64N; wave w = 16-wide N-subtile; K staged in 512B chunks.
__global__ __launch_bounds__(256) void k4_fc1(
    const uint8_t* __restrict__ fc1A, const uint32_t* __restrict__ wfF1,
    const float* __restrict__ bnp3, uint8_t* __restrict__ fc2A) {
    __shared__ __align__(16) uint8_t Ab[64 * 528];
    int t = threadIdx.x;
    int mb = blockIdx.x >> 3, nb = blockIdx.x & 7;
    int l = t & 63, w = t >> 6;
    int mlane = l & 15, kq = l >> 4;
    int o = nb * 64 + w * 16 + mlane;
    int nt = nb * 4 + w;
    const vi4* wf = (const vi4*)wfF1;
    vi4 acc[4];
#pragma unroll
    for (int i = 0; i < 4; i++) acc[i] = (vi4){0, 0, 0, 0};
    int row = t >> 2, seg = t & 3;
    const uint8_t* arow = fc1A + (size_t)(mb * 64 + row) * 4096 + seg * 128;
    for (int ch = 0; ch < 8; ch++) {
        if (ch) __syncthreads();
        const uint4* src = (const uint4*)(arow + ch * 512);
        uint4* dst = (uint4*)(Ab + row * 528 + seg * 128);
#pragma unroll
        for (int i = 0; i < 8; i++) dst[i] = src[i];
        __syncthreads();
#pragma unroll
        for (int s8 = 0; s8 < 8; s8++) {
            vi4 bfr = wf[(nt * 64 + ch * 8 + s8) * 64 + l];
#pragma unroll
            for (int ms = 0; ms < 4; ms++) {
                vi4 a = *(const vi4*)(Ab + (ms * 16 + mlane) * 528 +
                                      s8 * 64 + kq * 16);
                acc[ms] = __builtin_amdgcn_mfma_i32_16x16x64_i8(a, bfr, acc[ms], 0, 0, 0);
            }
        }
    }
    float4 p = ((const float4*)bnp3)[o];
#pragma unroll
    for (int ms = 0; ms < 4; ms++)
#pragma unroll
        for (int r = 0; r < 4; r++) {
            int m = mb * 64 + ms * 16 + kq * 4 + r;
            float h = __fadd_rn((float)acc[ms][r], p.z);
            float bv = __fadd_rn(__fmul_rn(h, p.x), p.y);
            fc2A[(size_t)m * 512 + o] = (uint8_t)(bv > 0.f ? 1 : 0xFF);
        }
}

// ---------------- k5: fc2 i8 GEMM [2048,512]x[512,256] + bn4 + clip ---------
__global__ __launch_bounds__(256) void k5_fc2(
    const uint8_t* __restrict__ fc2A, const uint32_t* __restrict__ wfF2,
    const float* __restrict__ bnp4, float* __restrict__ fc3A) {
    __shared__ __align__(16) uint8_t Ab[64 * 528];
    int t = threadIdx.x;
    int mb = blockIdx.x >> 2, nb = blockIdx.x & 3;
    int l = t & 63, w = t >> 6;
    int mlane = l & 15, kq = l >> 4;
    int o = nb * 64 + w * 16 + mlane;
    int nt = nb * 4 + w;
    const vi4* wf = (const vi4*)wfF2;
    vi4 acc[4];
#pragma unroll
    for (int i = 0; i < 4; i++) acc[i] = (vi4){0, 0, 0, 0};
    {
        int row = t >> 2, seg = t & 3;
        const uint4* src = (const uint4*)(fc2A + (size_t)(mb * 64 + row) * 512 +
                                          seg * 128);
        uint4* dst = (uint4*)(Ab + row * 528 + seg * 128);
#pragma unroll
        for (int i = 0; i < 8; i++) dst[i] = src[i];
    }
    __syncthreads();
#pragma unroll
    for (int s = 0; s < 8; s++) {
        vi4 bfr = wf[(nt * 8 + s) * 64 + l];
#pragma unroll
        for (int ms = 0; ms < 4; ms++) {
            vi4 a = *(const vi4*)(Ab + (ms * 16 + mlane) * 528 + s * 64 + kq * 16);
            acc[ms] = __builtin_amdgcn_mfma_i32_16x16x64_i8(a, bfr, acc[ms], 0, 0, 0);
        }
    }
    float4 p = ((const float4*)bnp4)[o];
#pragma unroll
    for (int ms = 0; ms < 4; ms++)
#pragma unroll
        for (int r = 0; r < 4; r++) {
            int m = mb * 64 + ms * 16 + kq * 4 + r;
            float h = __fadd_rn((float)acc[ms][r], p.z);
            float bv = __fadd_rn(__fmul_rn(h, p.x), p.y);
            bv = fminf(1.f, fmaxf(-1.f, bv));
            fc3A[(size_t)m * 256 + o] = bv;
        }
}

// ---------------- k6: fc3 + log_softmax (verbatim round-1) ----------------
__global__ __launch_bounds__(256) void k6_fc3_lsm(
    const float* __restrict__ h, const float* __restrict__ w,
    const float* __restrict__ fb, float* __restrict__ out) {
    int t = threadIdx.x;
    int wv_id = t >> 6, l = t & 63;
    int b = blockIdx.x * 4 + wv_id;
    const float4* hp = (const float4*)(h + (size_t)b * 256);
    float4 hv = hp[l];
    float logits[10];
#pragma unroll
    for (int j = 0; j < 10; j++) {
        const float4* wp4 = (const float4*)(w + j * 256);
        float4 w4 = wp4[l];
        float p = hv.x * w4.x + hv.y * w4.y + hv.z * w4.z + hv.w * w4.w;
#pragma unroll
        for (int off = 32; off > 0; off >>= 1) p += __shfl_xor(p, off, 64);
        logits[j] = p + fb[j];
    }
    float mx = logits[0];
#pragma unroll
    for (int j = 1; j < 10; j++) mx = fmaxf(mx, logits[j]);
    float sum = 0.f;
#pragma unroll
    for (int j = 0; j < 10; j++) sum += expf(logits[j] - mx);
    float ls = mx + logf(sum);
    if (l < 10) out[(size_t)b * 10 + l] = logits[l] - ls;
}

extern "C" void kernel_launch(void* const* d_in, const int* in_sizes, int n_in,
                              void* d_out, int out_size, void* d_ws, size_t ws_size,
                              hipStream_t stream) {
    (void)in_sizes; (void)n_in; (void)out_size; (void)ws_size;
    const float* x   = (const float*)d_in[0];
    const float* c1w = (const float*)d_in[1];
    const float* c1b = (const float*)d_in[2];
    const float* b1g = (const float*)d_in[3];
    const float* b1b = (const float*)d_in[4];
    const float* b1m = (const float*)d_in[5];
    const float* b1v = (const float*)d_in[6];
    const float* c2w = (const float*)d_in[7];
    const float* c2b = (const float*)d_in[8];
    const float* b2g = (const float*)d_in[9];
    const float* b2b = (const float*)d_in[10];
    const float* b2m = (const float*)d_in[11];
    const float* b2v = (const float*)d_in[12];
    const float* f1w = (const float*)d_in[13];
    const float* f1b = (const float*)d_in[14];
    const float* b3g = (const float*)d_in[15];
    const float* b3b = (const float*)d_in[16];
    const float* b3m = (const float*)d_in[17];
    const float* b3v = (const float*)d_in[18];
    const float* f2w = (const float*)d_in[19];
    const float* f2b = (const float*)d_in[20];
    const float* b4g = (const float*)d_in[21];
    const float* b4b = (const float*)d_in[22];
    const float* b4m = (const float*)d_in[23];
    const float* b4v = (const float*)d_in[24];
    const float* f3w = (const float*)d_in[25];
    const float* f3b = (const float*)d_in[26];
    float* out = (float*)d_out;

    uint8_t* ws = (uint8_t*)d_ws;
    uint8_t*  fc1A = ws + 0;                        // [2048,4096] i8   8 MB
    uint8_t*  fc2A = ws + 8388608;                  // [2048,512]  i8   1 MB
    float*    fc3A = (float*)   (ws + 9437184);     // [2048,256]  f32  2 MB
    float*    sw1  = (float*)   (ws + 11534336);    // [32,32]
    float*    bnp1 = (float*)   (ws + 11538432);
    float*    bnp2 = (float*)   (ws + 11538944);
    float*    bnp3 = (float*)   (ws + 11539968);
    float*    bnp4 = (float*)   (ws + 11548160);
    uint32_t* wfC2 = (uint32_t*)(ws + 11552256);    // 20 KB
    uint32_t* wfF2 = (uint32_t*)(ws + 11572736);    // 128 KB
    uint32_t* wfF1 = (uint32_t*)(ws + 11703808);    // 2 MB

    k0_pack<<<548, 256, 0, stream>>>(c1w, c2w, f1w, f2w, c1b, c2b, f1b, f2b,
                                     b1g, b1b, b1m, b1v, b2g, b2b, b2m, b2v,
                                     b3g, b3b, b3m, b3v, b4g, b4b, b4m, b4v,
                                     sw1, wfC2, wfF1, wfF2, bnp1, bnp2, bnp3, bnp4);
    k13_conv12<<<BSZ, 256, 0, stream>>>(x, sw1, bnp1, wfC2, bnp2, fc1A);
    k4_fc1<<<256, 256, 0, stream>>>(fc1A, wfF1, bnp3, fc2A);
    k5_fc2<<<128, 256, 0, stream>>>(fc2A, wfF2, bnp4, fc3A);
    k6_fc3_lsm<<<512, 256, 0, stream>>>(fc3A, f3w, f3b, out);
}